// Round 1
// baseline (660.463 us; speedup 1.0000x reference)
//
#include <hip/hip_runtime.h>
#include <hip/hip_bf16.h>
#include <stdint.h>

#define DEV __device__ __forceinline__

typedef __bf16 bf16x8 __attribute__((ext_vector_type(8)));
typedef float f32x4 __attribute__((ext_vector_type(4)));
typedef unsigned short ushort8_t __attribute__((ext_vector_type(8)));
typedef unsigned short ushort4_t __attribute__((ext_vector_type(4)));

constexpr int S = 2048;
constexpr int D = 4096;
constexpr int H = 32;
constexpr int HD = 128;

DEV unsigned short f2bf(float f) {
    uint32_t u = __builtin_bit_cast(uint32_t, f);
    u += 0x7fffu + ((u >> 16) & 1u);
    return (unsigned short)(u >> 16);
}
DEV float bf2f(unsigned short h) {
    uint32_t u = ((uint32_t)h) << 16;
    return __builtin_bit_cast(float, u);
}

DEV void gload_lds16(const void* g, void* l) {
    __builtin_amdgcn_global_load_lds(
        (const __attribute__((address_space(1))) void*)g,
        (__attribute__((address_space(3))) void*)l,
        16, 0, 0);
}

DEV f32x4 mfma16(bf16x8 a, bf16x8 b, f32x4 c) {
    return __builtin_amdgcn_mfma_f32_16x16x32_bf16(a, b, c, 0, 0, 0);
}

// ---------------- fp32 -> bf16 convert (8 elems/thread, exact grid) ---------
__global__ __launch_bounds__(256) void cvt_f32_bf16(const float* __restrict__ in,
                                                    unsigned short* __restrict__ out) {
    size_t i = (size_t)blockIdx.x * 256 + threadIdx.x;
    f32x4 a = ((const f32x4*)in)[2 * i];
    f32x4 b = ((const f32x4*)in)[2 * i + 1];
    ushort8_t o;
    o[0] = f2bf(a[0]); o[1] = f2bf(a[1]); o[2] = f2bf(a[2]); o[3] = f2bf(a[3]);
    o[4] = f2bf(b[0]); o[5] = f2bf(b[1]); o[6] = f2bf(b[2]); o[7] = f2bf(b[3]);
    ((ushort8_t*)out)[i] = o;
}

// ---------------- GEMM: C[m][n] = sum_k A[m][k] * B[n][k]  (both row-major, bf16)
// OMODE 0: bf16 C row-major [M][N];  1: bf16 C transposed [N][M];  2: fp32 C [M][N]
template <int OMODE>
__global__ __launch_bounds__(256) void gemm_bt(const unsigned short* __restrict__ A,
                                               const unsigned short* __restrict__ B,
                                               void* __restrict__ C,
                                               int M, int N, int K) {
    __shared__ unsigned short As[128 * 64];
    __shared__ unsigned short Bs[128 * 64];
    const int t = threadIdx.x;
    const int lane = t & 63;
    const int wid = t >> 6;
    const int g = lane >> 4;
    const int rl = lane & 15;
    const int m0 = blockIdx.y * 128;
    const int n0 = blockIdx.x * 128;
    const int wm = (wid >> 1) * 64;
    const int wn = (wid & 1) * 64;

    f32x4 acc[4][4] = {};

    for (int kt = 0; kt < K; kt += 64) {
        // stage 128x64 A-tile and B-tile; LDS layout [row][64] with 16B-chunk XOR
        // swizzle achieved by pre-swizzling the GLOBAL source (LDS dest linear).
#pragma unroll
        for (int r = 0; r < 4; ++r) {
            const int c = r * 256 + t;
            const int row = c >> 3;               // 8 chunks (16B) per 64-elem row
            const int src = (c & 7) ^ (row & 7);  // swizzled source chunk
            const int dstChunk = r * 256 + wid * 64;  // wave-uniform base
            gload_lds16(A + (size_t)(m0 + row) * K + kt + src * 8, &As[dstChunk * 8]);
            gload_lds16(B + (size_t)(n0 + row) * K + kt + src * 8, &Bs[dstChunk * 8]);
        }
        __syncthreads();
#pragma unroll
        for (int ks = 0; ks < 2; ++ks) {
            bf16x8 af[4], bfv[4];
#pragma unroll
            for (int i = 0; i < 4; ++i) {
                const int rowa = wm + i * 16 + rl;
                af[i] = *(const bf16x8*)&As[rowa * 64 + (((ks * 4 + g) ^ (rowa & 7)) << 3)];
                const int rowb = wn + i * 16 + rl;
                bfv[i] = *(const bf16x8*)&Bs[rowb * 64 + (((ks * 4 + g) ^ (rowb & 7)) << 3)];
            }
#pragma unroll
            for (int mi = 0; mi < 4; ++mi)
#pragma unroll
                for (int ni = 0; ni < 4; ++ni)
                    acc[mi][ni] = mfma16(af[mi], bfv[ni], acc[mi][ni]);
        }
        __syncthreads();
    }

#pragma unroll
    for (int mi = 0; mi < 4; ++mi) {
#pragma unroll
        for (int ni = 0; ni < 4; ++ni) {
            const int grow = m0 + wm + mi * 16 + g * 4;  // +r
            const int gcol = n0 + wn + ni * 16 + rl;
            if constexpr (OMODE == 0) {
                unsigned short* o = (unsigned short*)C;
#pragma unroll
                for (int r = 0; r < 4; ++r)
                    o[(size_t)(grow + r) * N + gcol] = f2bf(acc[mi][ni][r]);
            } else if constexpr (OMODE == 1) {
                unsigned short* o = (unsigned short*)C;
                ushort4_t v;
#pragma unroll
                for (int r = 0; r < 4; ++r) v[r] = f2bf(acc[mi][ni][r]);
                *(ushort4_t*)&o[(size_t)gcol * M + grow] = v;
            } else {
                float* o = (float*)C;
#pragma unroll
                for (int r = 0; r < 4; ++r)
                    o[(size_t)(grow + r) * N + gcol] = acc[mi][ni][r];
            }
        }
    }
}

// ---------------- RoPE in place on Q and K ([S][D] bf16) --------------------
__global__ __launch_bounds__(256) void rope_kernel(unsigned short* __restrict__ Qb,
                                                   unsigned short* __restrict__ Kb,
                                                   const float* __restrict__ cosT,
                                                   const float* __restrict__ sinT) {
    const int i = blockIdx.x * 256 + threadIdx.x;  // S*H*8 threads
    const int j8 = i & 7;
    const int h = (i >> 3) & 31;
    const int s = i >> 8;
    const size_t base = (size_t)s * D + h * HD + j8 * 8;
    const float* cp = cosT + s * HD + j8 * 8;
    const float* sp = sinT + s * HD + j8 * 8;
    float c1[8], s1[8], c2[8], s2[8];
#pragma unroll
    for (int k = 0; k < 8; ++k) { c1[k] = cp[k]; s1[k] = sp[k]; c2[k] = cp[k + 64]; s2[k] = sp[k + 64]; }

#pragma unroll
    for (int w = 0; w < 2; ++w) {
        unsigned short* p = (w == 0 ? Qb : Kb) + base;
        ushort8_t x1 = *(ushort8_t*)p;
        ushort8_t x2 = *(ushort8_t*)(p + 64);
        ushort8_t o1, o2;
#pragma unroll
        for (int k = 0; k < 8; ++k) {
            const float a = bf2f(x1[k]);
            const float b = bf2f(x2[k]);
            o1[k] = f2bf(a * c1[k] - b * s1[k]);
            o2[k] = f2bf(b * c2[k] + a * s2[k]);
        }
        *(ushort8_t*)p = o1;
        *(ushort8_t*)(p + 64) = o2;
    }
}

// ---------------- causal flash attention ------------------------------------
// Q,K: [S][D] bf16 (per head: row s, 128 contiguous). V: transposed [D][S] bf16.
// O: [S][D] bf16. Block = 4 waves; wave owns 16 q rows; KV tile = 64.
__global__ __launch_bounds__(256) void flash_attn(const unsigned short* __restrict__ Q,
                                                  const unsigned short* __restrict__ K,
                                                  const unsigned short* __restrict__ V,
                                                  unsigned short* __restrict__ O) {
    __shared__ unsigned short Ks[64 * 128];   // [kv][hd], swizzled
    __shared__ unsigned short Vs[128 * 64];   // [hd][kv], swizzled
    __shared__ unsigned short Ps[4][16 * 64]; // per-wave P, swizzled

    const int t = threadIdx.x;
    const int lane = t & 63;
    const int wid = t >> 6;
    const int g = lane >> 4;
    const int rl = lane & 15;
    const int qt = blockIdx.x;
    const int h = blockIdx.y;
    const int q0 = qt * 64;

    bf16x8 qf[4];
    {
        const unsigned short* qp = Q + (size_t)(q0 + wid * 16 + rl) * D + h * HD;
#pragma unroll
        for (int ks = 0; ks < 4; ++ks) qf[ks] = *(const bf16x8*)(qp + ks * 32 + g * 8);
    }

    f32x4 accO[8] = {};
    float m2[4], lsum[4];
#pragma unroll
    for (int r = 0; r < 4; ++r) { m2[r] = -1e30f; lsum[r] = 0.f; }

    constexpr float kSc = 0.08838834764831845f * 1.4426950408889634f; // scale*log2e
    const int qrow_base = q0 + wid * 16 + g * 4;
    const int ntiles = qt + 1;

    for (int kv = 0; kv < ntiles; ++kv) {
        const int kv0 = kv * 64;
#pragma unroll
        for (int r = 0; r < 4; ++r) {
            const int c = r * 256 + t;
            const int rowk = c >> 4;                 // 16 chunks per 128-elem row
            const int srck = (c & 15) ^ (rowk & 7);
            gload_lds16(K + (size_t)(kv0 + rowk) * D + h * HD + srck * 8,
                        &Ks[(r * 256 + wid * 64) * 8]);
            const int rowv = c >> 3;                 // 8 chunks per 64-elem row
            const int srcv = (c & 7) ^ (rowv & 7);
            gload_lds16(V + (size_t)(h * HD + rowv) * S + kv0 + srcv * 8,
                        &Vs[(r * 256 + wid * 64) * 8]);
        }
        __syncthreads();

        // S = Q K^T (scaled later): 4 n-tiles x 4 k-steps
        f32x4 sf[4] = {};
#pragma unroll
        for (int nt = 0; nt < 4; ++nt) {
            const int row = nt * 16 + rl;
#pragma unroll
            for (int ks = 0; ks < 4; ++ks) {
                bf16x8 kf = *(const bf16x8*)&Ks[row * 128 + (((ks * 4 + g) ^ (row & 7)) << 3)];
                sf[nt] = mfma16(qf[ks], kf, sf[nt]);
            }
        }

        // online softmax (base-2 domain)
        float cf[4];
#pragma unroll
        for (int r = 0; r < 4; ++r) {
            const int qrow = qrow_base + r;
            float mx = -1e30f;
#pragma unroll
            for (int nt = 0; nt < 4; ++nt) {
                float s = sf[nt][r] * kSc;
                const int kcol = kv0 + nt * 16 + rl;
                s = (kcol > qrow) ? -1e30f : s;
                sf[nt][r] = s;
                mx = fmaxf(mx, s);
            }
            mx = fmaxf(mx, __shfl_xor(mx, 1));
            mx = fmaxf(mx, __shfl_xor(mx, 2));
            mx = fmaxf(mx, __shfl_xor(mx, 4));
            mx = fmaxf(mx, __shfl_xor(mx, 8));
            const float mn = fmaxf(m2[r], mx);
            cf[r] = exp2f(m2[r] - mn);
            m2[r] = mn;
            float rs = 0.f;
#pragma unroll
            for (int nt = 0; nt < 4; ++nt) {
                const float p = exp2f(sf[nt][r] - mn);
                sf[nt][r] = p;
                rs += p;
            }
            rs += __shfl_xor(rs, 1);
            rs += __shfl_xor(rs, 2);
            rs += __shfl_xor(rs, 4);
            rs += __shfl_xor(rs, 8);
            lsum[r] = lsum[r] * cf[r] + rs;
        }

#pragma unroll
        for (int nt = 0; nt < 8; ++nt)
#pragma unroll
            for (int r = 0; r < 4; ++r) accO[nt][r] *= cf[r];

        // P -> LDS (bf16, swizzled), per-wave region
        unsigned short* myP = Ps[wid];
#pragma unroll
        for (int nt = 0; nt < 4; ++nt) {
#pragma unroll
            for (int r = 0; r < 4; ++r) {
                const int row = g * 4 + r;
                const int col = nt * 16 + rl;
                myP[row * 64 + (col ^ ((row & 7) << 3))] = f2bf(sf[nt][r]);
            }
        }
        __syncthreads();

        // O += P V : 8 hd-tiles x 2 k-steps
#pragma unroll
        for (int ks = 0; ks < 2; ++ks) {
            const int k0 = ks * 32 + g * 8;
            bf16x8 pa = *(const bf16x8*)&myP[rl * 64 + (k0 ^ ((rl & 7) << 3))];
#pragma unroll
            for (int nt = 0; nt < 8; ++nt) {
                const int vrow = nt * 16 + rl;
                bf16x8 vf = *(const bf16x8*)&Vs[vrow * 64 + (((ks * 4 + g) ^ (vrow & 7)) << 3)];
                accO[nt] = mfma16(pa, vf, accO[nt]);
            }
        }
        __syncthreads();
    }

#pragma unroll
    for (int r = 0; r < 4; ++r) {
        const float inv = 1.0f / lsum[r];
#pragma unroll
        for (int nt = 0; nt < 8; ++nt)
            O[(size_t)(qrow_base + r) * D + h * HD + nt * 16 + rl] = f2bf(accO[nt][r] * inv);
    }
}

// ---------------- launch ----------------------------------------------------
extern "C" void kernel_launch(void* const* d_in, const int* in_sizes, int n_in,
                              void* d_out, int out_size, void* d_ws, size_t ws_size,
                              hipStream_t stream) {
    const float* hs   = (const float*)d_in[0];
    // d_in[1] = attention_mask (pure causal; implemented directly)
    const float* cosT = (const float*)d_in[2];
    const float* sinT = (const float*)d_in[3];
    const float* Wq   = (const float*)d_in[4];
    const float* Wk   = (const float*)d_in[5];
    const float* Wv   = (const float*)d_in[6];
    const float* Wo   = (const float*)d_in[7];

    char* ws = (char*)d_ws;
    const size_t MB = 1ull << 20;
    unsigned short* hsb = (unsigned short*)(ws);             // 16 MB  [S][D]
    unsigned short* wqb = (unsigned short*)(ws + 16 * MB);   // 32 MB  [D][D]
    unsigned short* wkb = (unsigned short*)(ws + 48 * MB);
    unsigned short* wvb = (unsigned short*)(ws + 80 * MB);
    unsigned short* wob = (unsigned short*)(ws + 112 * MB);
    unsigned short* Qb  = (unsigned short*)(ws + 144 * MB);  // 16 MB [S][D]
    unsigned short* Kb  = (unsigned short*)(ws + 160 * MB);  // 16 MB [S][D]
    unsigned short* Vt  = (unsigned short*)(ws + 176 * MB);  // 16 MB [D][S] (V^T)
    unsigned short* AOb = (unsigned short*)(ws + 192 * MB);  // 16 MB [S][D]

    cvt_f32_bf16<<<4096, 256, 0, stream>>>(hs, hsb);
    cvt_f32_bf16<<<8192, 256, 0, stream>>>(Wq, wqb);
    cvt_f32_bf16<<<8192, 256, 0, stream>>>(Wk, wkb);
    cvt_f32_bf16<<<8192, 256, 0, stream>>>(Wv, wvb);
    cvt_f32_bf16<<<8192, 256, 0, stream>>>(Wo, wob);

    dim3 gg(D / 128, S / 128);
    gemm_bt<0><<<gg, 256, 0, stream>>>(hsb, wqb, Qb, S, D, D);
    gemm_bt<0><<<gg, 256, 0, stream>>>(hsb, wkb, Kb, S, D, D);
    gemm_bt<1><<<gg, 256, 0, stream>>>(hsb, wvb, Vt, S, D, D);

    rope_kernel<<<2048, 256, 0, stream>>>(Qb, Kb, cosT, sinT);

    flash_attn<<<dim3(S / 64, H), 256, 0, stream>>>(Qb, Kb, Vt, AOb);

    gemm_bt<2><<<gg, 256, 0, stream>>>(AOb, wob, (float*)d_out, S, D, D);
}

// Round 2
// 613.704 us; speedup vs baseline: 1.0762x; 1.0762x over previous
//
#include <hip/hip_runtime.h>
#include <hip/hip_bf16.h>
#include <stdint.h>

#define DEV __device__ __forceinline__

typedef __bf16 bf16x8 __attribute__((ext_vector_type(8)));
typedef float f32x4 __attribute__((ext_vector_type(4)));
typedef unsigned short ushort8_t __attribute__((ext_vector_type(8)));
typedef unsigned short ushort4_t __attribute__((ext_vector_type(4)));

constexpr int S = 2048;
constexpr int D = 4096;
constexpr int H = 32;
constexpr int HD = 128;

DEV unsigned short f2bf(float f) {
    uint32_t u = __builtin_bit_cast(uint32_t, f);
    u += 0x7fffu + ((u >> 16) & 1u);
    return (unsigned short)(u >> 16);
}
DEV float bf2f(unsigned short h) {
    uint32_t u = ((uint32_t)h) << 16;
    return __builtin_bit_cast(float, u);
}

DEV void gload_lds16(const void* g, void* l) {
    __builtin_amdgcn_global_load_lds(
        (const __attribute__((address_space(1))) void*)g,
        (__attribute__((address_space(3))) void*)l,
        16, 0, 0);
}

DEV f32x4 mfma16(bf16x8 a, bf16x8 b, f32x4 c) {
    return __builtin_amdgcn_mfma_f32_16x16x32_bf16(a, b, c, 0, 0, 0);
}

// ---------------- fp32 -> bf16 convert (8 elems/thread, exact grid) ---------
__global__ __launch_bounds__(256) void cvt_f32_bf16(const float* __restrict__ in,
                                                    unsigned short* __restrict__ out) {
    size_t i = (size_t)blockIdx.x * 256 + threadIdx.x;
    f32x4 a = ((const f32x4*)in)[2 * i];
    f32x4 b = ((const f32x4*)in)[2 * i + 1];
    ushort8_t o;
    o[0] = f2bf(a[0]); o[1] = f2bf(a[1]); o[2] = f2bf(a[2]); o[3] = f2bf(a[3]);
    o[4] = f2bf(b[0]); o[5] = f2bf(b[1]); o[6] = f2bf(b[2]); o[7] = f2bf(b[3]);
    ((ushort8_t*)out)[i] = o;
}

// ---------------- GEMM: C[m][n] = sum_k A[m][k] * B[n][k]  (both row-major, bf16)
// OMODE 0: bf16 C row-major [M][N];  1: bf16 C transposed [N][M];  2: fp32 C [M][N]
template <int OMODE>
__global__ __launch_bounds__(256) void gemm_bt(const unsigned short* __restrict__ A,
                                               const unsigned short* __restrict__ B,
                                               void* __restrict__ C,
                                               int M, int N, int K) {
    __shared__ unsigned short As[128 * 64];
    __shared__ unsigned short Bs[128 * 64];
    const int t = threadIdx.x;
    const int lane = t & 63;
    const int wid = t >> 6;
    const int g = lane >> 4;
    const int rl = lane & 15;
    const int m0 = blockIdx.y * 128;
    const int n0 = blockIdx.x * 128;
    const int wm = (wid >> 1) * 64;
    const int wn = (wid & 1) * 64;

    f32x4 acc[4][4] = {};

    for (int kt = 0; kt < K; kt += 64) {
#pragma unroll
        for (int r = 0; r < 4; ++r) {
            const int c = r * 256 + t;
            const int row = c >> 3;               // 8 chunks (16B) per 64-elem row
            const int src = (c & 7) ^ (row & 7);  // swizzled source chunk
            const int dstChunk = r * 256 + wid * 64;  // wave-uniform base
            gload_lds16(A + (size_t)(m0 + row) * K + kt + src * 8, &As[dstChunk * 8]);
            gload_lds16(B + (size_t)(n0 + row) * K + kt + src * 8, &Bs[dstChunk * 8]);
        }
        __syncthreads();
#pragma unroll
        for (int ks = 0; ks < 2; ++ks) {
            bf16x8 af[4], bfv[4];
#pragma unroll
            for (int i = 0; i < 4; ++i) {
                const int rowa = wm + i * 16 + rl;
                af[i] = *(const bf16x8*)&As[rowa * 64 + (((ks * 4 + g) ^ (rowa & 7)) << 3)];
                const int rowb = wn + i * 16 + rl;
                bfv[i] = *(const bf16x8*)&Bs[rowb * 64 + (((ks * 4 + g) ^ (rowb & 7)) << 3)];
            }
#pragma unroll
            for (int mi = 0; mi < 4; ++mi)
#pragma unroll
                for (int ni = 0; ni < 4; ++ni)
                    acc[mi][ni] = mfma16(af[mi], bfv[ni], acc[mi][ni]);
        }
        __syncthreads();
    }

#pragma unroll
    for (int mi = 0; mi < 4; ++mi) {
#pragma unroll
        for (int ni = 0; ni < 4; ++ni) {
            const int grow = m0 + wm + mi * 16 + g * 4;  // +r
            const int gcol = n0 + wn + ni * 16 + rl;
            if constexpr (OMODE == 0) {
                unsigned short* o = (unsigned short*)C;
#pragma unroll
                for (int r = 0; r < 4; ++r)
                    o[(size_t)(grow + r) * N + gcol] = f2bf(acc[mi][ni][r]);
            } else if constexpr (OMODE == 1) {
                unsigned short* o = (unsigned short*)C;
                ushort4_t v;
#pragma unroll
                for (int r = 0; r < 4; ++r) v[r] = f2bf(acc[mi][ni][r]);
                *(ushort4_t*)&o[(size_t)gcol * M + grow] = v;
            } else {
                float* o = (float*)C;
#pragma unroll
                for (int r = 0; r < 4; ++r)
                    o[(size_t)(grow + r) * N + gcol] = acc[mi][ni][r];
            }
        }
    }
}

// ---------------- RoPE in place on Q and K ([S][D] bf16) --------------------
__global__ __launch_bounds__(256) void rope_kernel(unsigned short* __restrict__ Qb,
                                                   unsigned short* __restrict__ Kb,
                                                   const float* __restrict__ cosT,
                                                   const float* __restrict__ sinT) {
    const int i = blockIdx.x * 256 + threadIdx.x;  // S*H*8 threads
    const int j8 = i & 7;
    const int h = (i >> 3) & 31;
    const int s = i >> 8;
    const size_t base = (size_t)s * D + h * HD + j8 * 8;
    const float* cp = cosT + s * HD + j8 * 8;
    const float* sp = sinT + s * HD + j8 * 8;
    float c1[8], s1[8], c2[8], s2[8];
#pragma unroll
    for (int k = 0; k < 8; ++k) { c1[k] = cp[k]; s1[k] = sp[k]; c2[k] = cp[k + 64]; s2[k] = sp[k + 64]; }

#pragma unroll
    for (int w = 0; w < 2; ++w) {
        unsigned short* p = (w == 0 ? Qb : Kb) + base;
        ushort8_t x1 = *(ushort8_t*)p;
        ushort8_t x2 = *(ushort8_t*)(p + 64);
        ushort8_t o1, o2;
#pragma unroll
        for (int k = 0; k < 8; ++k) {
            const float a = bf2f(x1[k]);
            const float b = bf2f(x2[k]);
            o1[k] = f2bf(a * c1[k] - b * s1[k]);
            o2[k] = f2bf(b * c2[k] + a * s2[k]);
        }
        *(ushort8_t*)p = o1;
        *(ushort8_t*)(p + 64) = o2;
    }
}

// ---------------- causal flash attention ------------------------------------
// Q,K: [S][D] bf16. V: transposed [D][S] bf16. O: [S][D] bf16.
// Block = 4 waves x 32 q-rows = 128-row q tile. KV tile = 64. K double-buffered.
constexpr int NQT = S / 128;  // 16 q-tiles
__global__ __launch_bounds__(256, 2) void flash_attn(const unsigned short* __restrict__ Q,
                                                     const unsigned short* __restrict__ K,
                                                     const unsigned short* __restrict__ V,
                                                     unsigned short* __restrict__ O) {
    __shared__ unsigned short Ks[2][64 * 128];  // [kv][hd], swizzled, dbuf
    __shared__ unsigned short Vs[128 * 64];     // [hd][kv], swizzled
    __shared__ unsigned short Ps[4][32 * 64];   // per-wave P, swizzled

    const int t = threadIdx.x;
    const int lane = t & 63;
    const int wid = t >> 6;
    const int g = lane >> 4;
    const int rl = lane & 15;
    const int bid = blockIdx.x;
    const int qt = (NQT - 1) - (bid >> 5);  // heavy tiles first
    const int h = bid & 31;                 // head in low bits: head-affine XCD
    const int q0 = qt * 128;
    const int wrow0 = q0 + wid * 32;

    bf16x8 qf[2][4];
#pragma unroll
    for (int mi = 0; mi < 2; ++mi) {
        const unsigned short* qp = Q + (size_t)(wrow0 + mi * 16 + rl) * D + h * HD;
#pragma unroll
        for (int ks = 0; ks < 4; ++ks) qf[mi][ks] = *(const bf16x8*)(qp + ks * 32 + g * 8);
    }

    f32x4 accO[2][8] = {};
    float m2[2][4], lsum[2][4];
#pragma unroll
    for (int mi = 0; mi < 2; ++mi)
#pragma unroll
        for (int r = 0; r < 4; ++r) { m2[mi][r] = -1e30f; lsum[mi][r] = 0.f; }

    constexpr float kSc = 0.08838834764831845f * 1.4426950408889634f;  // scale*log2e

    // prologue: stage K tile 0 into buf 0
#pragma unroll
    for (int r = 0; r < 4; ++r) {
        const int c = r * 256 + t;
        const int rowk = c >> 4;
        const int srck = (c & 15) ^ (rowk & 7);
        gload_lds16(K + (size_t)rowk * D + h * HD + srck * 8,
                    &Ks[0][(r * 256 + wid * 64) * 8]);
    }
    __syncthreads();

    int cur = 0;
    const int ntiles = 2 * qt + 2;
    for (int kv = 0; kv < ntiles; ++kv) {
        const int kv0 = kv * 64;
        // stage V[kv] (single buffer) + prefetch K[kv+1] into other buffer
#pragma unroll
        for (int r = 0; r < 4; ++r) {
            const int c = r * 256 + t;
            const int rowv = c >> 3;
            const int srcv = (c & 7) ^ (rowv & 7);
            gload_lds16(V + (size_t)(h * HD + rowv) * S + kv0 + srcv * 8,
                        &Vs[(r * 256 + wid * 64) * 8]);
        }
        if (kv + 1 < ntiles) {
#pragma unroll
            for (int r = 0; r < 4; ++r) {
                const int c = r * 256 + t;
                const int rowk = c >> 4;
                const int srck = (c & 15) ^ (rowk & 7);
                gload_lds16(K + (size_t)(kv0 + 64 + rowk) * D + h * HD + srck * 8,
                            &Ks[cur ^ 1][(r * 256 + wid * 64) * 8]);
            }
        }

        const bool active = kv0 <= wrow0 + 31;  // wave-uniform
        if (active) {
            // S = Q K^T
            f32x4 sf[2][4];
#pragma unroll
            for (int mi = 0; mi < 2; ++mi)
#pragma unroll
                for (int nt = 0; nt < 4; ++nt) sf[mi][nt] = f32x4{0.f, 0.f, 0.f, 0.f};
#pragma unroll
            for (int nt = 0; nt < 4; ++nt) {
                const int row = nt * 16 + rl;
#pragma unroll
                for (int ks = 0; ks < 4; ++ks) {
                    bf16x8 kf = *(const bf16x8*)&Ks[cur][row * 128 + (((ks * 4 + g) ^ (row & 7)) << 3)];
                    sf[0][nt] = mfma16(qf[0][ks], kf, sf[0][nt]);
                    sf[1][nt] = mfma16(qf[1][ks], kf, sf[1][nt]);
                }
            }

            const bool needMask = (kv0 + 63 > wrow0);  // wave-uniform
            float cf[2][4];
            bool chg = false;
#pragma unroll
            for (int mi = 0; mi < 2; ++mi) {
#pragma unroll
                for (int r = 0; r < 4; ++r) {
                    const int qrow = wrow0 + mi * 16 + g * 4 + r;
                    float mx = -1e30f;
#pragma unroll
                    for (int nt = 0; nt < 4; ++nt) {
                        float s = sf[mi][nt][r] * kSc;
                        if (needMask) {
                            const int kcol = kv0 + nt * 16 + rl;
                            s = (kcol > qrow) ? -1e30f : s;
                        }
                        sf[mi][nt][r] = s;
                        mx = fmaxf(mx, s);
                    }
                    mx = fmaxf(mx, __shfl_xor(mx, 1));
                    mx = fmaxf(mx, __shfl_xor(mx, 2));
                    mx = fmaxf(mx, __shfl_xor(mx, 4));
                    mx = fmaxf(mx, __shfl_xor(mx, 8));
                    const float mn = fmaxf(m2[mi][r], mx);
                    cf[mi][r] = exp2f(m2[mi][r] - mn);
                    chg |= (mn > m2[mi][r]);
                    m2[mi][r] = mn;
                    float rs = 0.f;
#pragma unroll
                    for (int nt = 0; nt < 4; ++nt) {
                        const float p = exp2f(sf[mi][nt][r] - mn);
                        sf[mi][nt][r] = p;
                        rs += p;
                    }
                    rs += __shfl_xor(rs, 1);
                    rs += __shfl_xor(rs, 2);
                    rs += __shfl_xor(rs, 4);
                    rs += __shfl_xor(rs, 8);
                    lsum[mi][r] = lsum[mi][r] * cf[mi][r] + rs;
                }
            }

            if (__any((int)chg)) {
#pragma unroll
                for (int mi = 0; mi < 2; ++mi)
#pragma unroll
                    for (int nt = 0; nt < 8; ++nt)
#pragma unroll
                        for (int r = 0; r < 4; ++r) accO[mi][nt][r] *= cf[mi][r];
            }

            // P -> LDS (bf16, swizzled), per-wave region
            unsigned short* myP = Ps[wid];
#pragma unroll
            for (int mi = 0; mi < 2; ++mi)
#pragma unroll
                for (int nt = 0; nt < 4; ++nt)
#pragma unroll
                    for (int r = 0; r < 4; ++r) {
                        const int row = mi * 16 + g * 4 + r;
                        const int col = nt * 16 + rl;
                        myP[row * 64 + (col ^ ((row & 7) << 3))] = f2bf(sf[mi][nt][r]);
                    }
        }
        __syncthreads();  // drains V + K-next staging; orders P (per-wave anyway)

        if (active) {
            unsigned short* myP = Ps[wid];
#pragma unroll
            for (int ks = 0; ks < 2; ++ks) {
                const int k0 = ks * 32 + g * 8;
                bf16x8 pa[2];
#pragma unroll
                for (int mi = 0; mi < 2; ++mi) {
                    const int row = mi * 16 + rl;
                    pa[mi] = *(const bf16x8*)&myP[row * 64 + (k0 ^ ((row & 7) << 3))];
                }
#pragma unroll
                for (int nt = 0; nt < 8; ++nt) {
                    const int vrow = nt * 16 + rl;
                    bf16x8 vf = *(const bf16x8*)&Vs[vrow * 64 + (((ks * 4 + g) ^ (vrow & 7)) << 3)];
                    accO[0][nt] = mfma16(pa[0], vf, accO[0][nt]);
                    accO[1][nt] = mfma16(pa[1], vf, accO[1][nt]);
                }
            }
        }
        __syncthreads();  // all PV reads done before next iter's V stage
        cur ^= 1;
    }

#pragma unroll
    for (int mi = 0; mi < 2; ++mi)
#pragma unroll
        for (int r = 0; r < 4; ++r) {
            const float inv = 1.0f / lsum[mi][r];
            const int qrow = wrow0 + mi * 16 + g * 4 + r;
#pragma unroll
            for (int nt = 0; nt < 8; ++nt)
                O[(size_t)qrow * D + h * HD + nt * 16 + rl] = f2bf(accO[mi][nt][r] * inv);
        }
}

// ---------------- launch ----------------------------------------------------
extern "C" void kernel_launch(void* const* d_in, const int* in_sizes, int n_in,
                              void* d_out, int out_size, void* d_ws, size_t ws_size,
                              hipStream_t stream) {
    const float* hs   = (const float*)d_in[0];
    const float* cosT = (const float*)d_in[2];
    const float* sinT = (const float*)d_in[3];
    const float* Wq   = (const float*)d_in[4];
    const float* Wk   = (const float*)d_in[5];
    const float* Wv   = (const float*)d_in[6];
    const float* Wo   = (const float*)d_in[7];

    char* ws = (char*)d_ws;
    const size_t MB = 1ull << 20;
    unsigned short* hsb = (unsigned short*)(ws);             // 16 MB  [S][D]
    unsigned short* wqb = (unsigned short*)(ws + 16 * MB);   // 32 MB  [D][D]
    unsigned short* wkb = (unsigned short*)(ws + 48 * MB);
    unsigned short* wvb = (unsigned short*)(ws + 80 * MB);
    unsigned short* wob = (unsigned short*)(ws + 112 * MB);
    unsigned short* Qb  = (unsigned short*)(ws + 144 * MB);  // 16 MB [S][D]
    unsigned short* Kb  = (unsigned short*)(ws + 160 * MB);  // 16 MB [S][D]
    unsigned short* Vt  = (unsigned short*)(ws + 176 * MB);  // 16 MB [D][S] (V^T)
    unsigned short* AOb = (unsigned short*)(ws + 192 * MB);  // 16 MB [S][D]

    cvt_f32_bf16<<<4096, 256, 0, stream>>>(hs, hsb);
    cvt_f32_bf16<<<8192, 256, 0, stream>>>(Wq, wqb);
    cvt_f32_bf16<<<8192, 256, 0, stream>>>(Wk, wkb);
    cvt_f32_bf16<<<8192, 256, 0, stream>>>(Wv, wvb);
    cvt_f32_bf16<<<8192, 256, 0, stream>>>(Wo, wob);

    dim3 gg(D / 128, S / 128);
    gemm_bt<0><<<gg, 256, 0, stream>>>(hsb, wqb, Qb, S, D, D);
    gemm_bt<0><<<gg, 256, 0, stream>>>(hsb, wkb, Kb, S, D, D);
    gemm_bt<1><<<gg, 256, 0, stream>>>(hsb, wvb, Vt, S, D, D);

    rope_kernel<<<2048, 256, 0, stream>>>(Qb, Kb, cosT, sinT);

    flash_attn<<<dim3(NQT * H), 256, 0, stream>>>(Qb, Kb, Vt, AOb);

    gemm_bt<2><<<gg, 256, 0, stream>>>(AOb, wob, (float*)d_out, S, D, D);
}

// Round 3
// 554.125 us; speedup vs baseline: 1.1919x; 1.1075x over previous
//
#include <hip/hip_runtime.h>
#include <hip/hip_bf16.h>
#include <stdint.h>

#define DEV __device__ __forceinline__

typedef __bf16 bf16x8 __attribute__((ext_vector_type(8)));
typedef float f32x4 __attribute__((ext_vector_type(4)));
typedef unsigned short ushort8_t __attribute__((ext_vector_type(8)));
typedef unsigned short ushort4_t __attribute__((ext_vector_type(4)));

constexpr int S = 2048;
constexpr int D = 4096;
constexpr int H = 32;
constexpr int HD = 128;
constexpr float kSc = 0.08838834764831845f * 1.4426950408889634f;  // 1/sqrt(HD) * log2(e)

DEV unsigned short f2bf(float f) {
    uint32_t u = __builtin_bit_cast(uint32_t, f);
    u += 0x7fffu + ((u >> 16) & 1u);
    return (unsigned short)(u >> 16);
}
DEV float bf2f(unsigned short h) {
    uint32_t u = ((uint32_t)h) << 16;
    return __builtin_bit_cast(float, u);
}

DEV void gload_lds16(const void* g, void* l) {
    __builtin_amdgcn_global_load_lds(
        (const __attribute__((address_space(1))) void*)g,
        (__attribute__((address_space(3))) void*)l,
        16, 0, 0);
}

DEV f32x4 mfma16(bf16x8 a, bf16x8 b, f32x4 c) {
    return __builtin_amdgcn_mfma_f32_16x16x32_bf16(a, b, c, 0, 0, 0);
}

// ---------------- fp32 -> bf16 convert (8 elems/thread, exact grid) ---------
__global__ __launch_bounds__(256) void cvt_f32_bf16(const float* __restrict__ in,
                                                    unsigned short* __restrict__ out) {
    size_t i = (size_t)blockIdx.x * 256 + threadIdx.x;
    f32x4 a = ((const f32x4*)in)[2 * i];
    f32x4 b = ((const f32x4*)in)[2 * i + 1];
    ushort8_t o;
    o[0] = f2bf(a[0]); o[1] = f2bf(a[1]); o[2] = f2bf(a[2]); o[3] = f2bf(a[3]);
    o[4] = f2bf(b[0]); o[5] = f2bf(b[1]); o[6] = f2bf(b[2]); o[7] = f2bf(b[3]);
    ((ushort8_t*)out)[i] = o;
}

// ---------------- GEMM: C[m][n] = sum_k A[m][k] * B[n][k]  (both row-major, bf16)
// OMODE 0: bf16 C row-major [M][N];  1: bf16 C transposed [N][M];  2: fp32 C [M][N]
template <int OMODE>
__global__ __launch_bounds__(256) void gemm_bt(const unsigned short* __restrict__ A,
                                               const unsigned short* __restrict__ B,
                                               void* __restrict__ C,
                                               int M, int N, int K) {
    __shared__ unsigned short As[128 * 64];
    __shared__ unsigned short Bs[128 * 64];
    const int t = threadIdx.x;
    const int lane = t & 63;
    const int wid = t >> 6;
    const int g = lane >> 4;
    const int rl = lane & 15;
    const int m0 = blockIdx.y * 128;
    const int n0 = blockIdx.x * 128;
    const int wm = (wid >> 1) * 64;
    const int wn = (wid & 1) * 64;

    f32x4 acc[4][4] = {};

    for (int kt = 0; kt < K; kt += 64) {
#pragma unroll
        for (int r = 0; r < 4; ++r) {
            const int c = r * 256 + t;
            const int row = c >> 3;               // 8 chunks (16B) per 64-elem row
            const int src = (c & 7) ^ (row & 7);  // swizzled source chunk
            const int dstChunk = r * 256 + wid * 64;  // wave-uniform base
            gload_lds16(A + (size_t)(m0 + row) * K + kt + src * 8, &As[dstChunk * 8]);
            gload_lds16(B + (size_t)(n0 + row) * K + kt + src * 8, &Bs[dstChunk * 8]);
        }
        __syncthreads();
#pragma unroll
        for (int ks = 0; ks < 2; ++ks) {
            bf16x8 af[4], bfv[4];
#pragma unroll
            for (int i = 0; i < 4; ++i) {
                const int rowa = wm + i * 16 + rl;
                af[i] = *(const bf16x8*)&As[rowa * 64 + (((ks * 4 + g) ^ (rowa & 7)) << 3)];
                const int rowb = wn + i * 16 + rl;
                bfv[i] = *(const bf16x8*)&Bs[rowb * 64 + (((ks * 4 + g) ^ (rowb & 7)) << 3)];
            }
#pragma unroll
            for (int mi = 0; mi < 4; ++mi)
#pragma unroll
                for (int ni = 0; ni < 4; ++ni)
                    acc[mi][ni] = mfma16(af[mi], bfv[ni], acc[mi][ni]);
        }
        __syncthreads();
    }

#pragma unroll
    for (int mi = 0; mi < 4; ++mi) {
#pragma unroll
        for (int ni = 0; ni < 4; ++ni) {
            const int grow = m0 + wm + mi * 16 + g * 4;  // +r
            const int gcol = n0 + wn + ni * 16 + rl;
            if constexpr (OMODE == 0) {
                unsigned short* o = (unsigned short*)C;
#pragma unroll
                for (int r = 0; r < 4; ++r)
                    o[(size_t)(grow + r) * N + gcol] = f2bf(acc[mi][ni][r]);
            } else if constexpr (OMODE == 1) {
                unsigned short* o = (unsigned short*)C;
                ushort4_t v;
#pragma unroll
                for (int r = 0; r < 4; ++r) v[r] = f2bf(acc[mi][ni][r]);
                *(ushort4_t*)&o[(size_t)gcol * M + grow] = v;
            } else {
                float* o = (float*)C;
#pragma unroll
                for (int r = 0; r < 4; ++r)
                    o[(size_t)(grow + r) * N + gcol] = acc[mi][ni][r];
            }
        }
    }
}

// ---------------- RoPE in place on Q and K ([S][D] bf16) --------------------
// Q additionally pre-scaled by 1/sqrt(HD)*log2e so attention scores come out
// of the QK^T MFMA already in the exp2 domain.
__global__ __launch_bounds__(256) void rope_kernel(unsigned short* __restrict__ Qb,
                                                   unsigned short* __restrict__ Kb,
                                                   const float* __restrict__ cosT,
                                                   const float* __restrict__ sinT) {
    const int i = blockIdx.x * 256 + threadIdx.x;  // S*H*8 threads
    const int j8 = i & 7;
    const int h = (i >> 3) & 31;
    const int s = i >> 8;
    const size_t base = (size_t)s * D + h * HD + j8 * 8;
    const float* cp = cosT + s * HD + j8 * 8;
    const float* sp = sinT + s * HD + j8 * 8;
    float c1[8], s1[8], c2[8], s2[8];
#pragma unroll
    for (int k = 0; k < 8; ++k) { c1[k] = cp[k]; s1[k] = sp[k]; c2[k] = cp[k + 64]; s2[k] = sp[k + 64]; }

#pragma unroll
    for (int w = 0; w < 2; ++w) {
        unsigned short* p = (w == 0 ? Qb : Kb) + base;
        const float f = (w == 0) ? kSc : 1.0f;
        ushort8_t x1 = *(ushort8_t*)p;
        ushort8_t x2 = *(ushort8_t*)(p + 64);
        ushort8_t o1, o2;
#pragma unroll
        for (int k = 0; k < 8; ++k) {
            const float a = bf2f(x1[k]);
            const float b = bf2f(x2[k]);
            o1[k] = f2bf((a * c1[k] - b * s1[k]) * f);
            o2[k] = f2bf((b * c2[k] + a * s2[k]) * f);
        }
        *(ushort8_t*)p = o1;
        *(ushort8_t*)(p + 64) = o2;
    }
}

// ---------------- causal flash attention (swapped-operand MFMA) -------------
// Q,K: [S][D] bf16. V: transposed [D][S] bf16. O: [S][D] bf16.
// Block = 4 waves x 32 q-rows = 128-row q tile. KV tile = 64. K double-buffered.
// QK^T computed as mfma(K,Q) -> lane holds S[q=lane&15][k=g*4+r] per nt:
// row reduction = 15 in-reg ops + 2 shfl_xor. PV as mfma(V,P) keeps the same
// q=lane&15 mapping in the O accumulator.
constexpr int NQT = S / 128;  // 16 q-tiles
__global__ __launch_bounds__(256, 2) void flash_attn(const unsigned short* __restrict__ Q,
                                                     const unsigned short* __restrict__ K,
                                                     const unsigned short* __restrict__ V,
                                                     unsigned short* __restrict__ O) {
    __shared__ unsigned short Ks[2][64 * 128];  // [kv][hd], swizzled, dbuf
    __shared__ unsigned short Vs[128 * 64];     // [hd][kv], swizzled
    __shared__ unsigned short Ps[4][32 * 64];   // per-wave P, swizzled

    const int t = threadIdx.x;
    const int lane = t & 63;
    const int wid = t >> 6;
    const int g = lane >> 4;
    const int rl = lane & 15;
    const int bid = blockIdx.x;
    const int qt = (NQT - 1) - (bid >> 5);  // heavy tiles first
    const int h = bid & 31;                 // head in low bits: head-affine XCD
    const int q0 = qt * 128;
    const int wrow0 = q0 + wid * 32;

    bf16x8 qf[2][4];
#pragma unroll
    for (int mi = 0; mi < 2; ++mi) {
        const unsigned short* qp = Q + (size_t)(wrow0 + mi * 16 + rl) * D + h * HD;
#pragma unroll
        for (int ks = 0; ks < 4; ++ks) qf[mi][ks] = *(const bf16x8*)(qp + ks * 32 + g * 8);
    }

    f32x4 accO[2][8] = {};
    float m2s[2] = {-1e30f, -1e30f};
    float lsum[2] = {0.f, 0.f};

    // prologue: stage K tile 0 into buf 0
#pragma unroll
    for (int r = 0; r < 4; ++r) {
        const int c = r * 256 + t;
        const int rowk = c >> 4;
        const int srck = (c & 15) ^ (rowk & 7);
        gload_lds16(K + (size_t)rowk * D + h * HD + srck * 8,
                    &Ks[0][(r * 256 + wid * 64) * 8]);
    }
    __syncthreads();

    int cur = 0;
    const int ntiles = 2 * qt + 2;
    for (int kv = 0; kv < ntiles; ++kv) {
        const int kv0 = kv * 64;
        // stage V[kv] (single buffer) + prefetch K[kv+1] into other buffer
#pragma unroll
        for (int r = 0; r < 4; ++r) {
            const int c = r * 256 + t;
            const int rowv = c >> 3;
            const int srcv = (c & 7) ^ (rowv & 7);
            gload_lds16(V + (size_t)(h * HD + rowv) * S + kv0 + srcv * 8,
                        &Vs[(r * 256 + wid * 64) * 8]);
        }
        if (kv + 1 < ntiles) {
#pragma unroll
            for (int r = 0; r < 4; ++r) {
                const int c = r * 256 + t;
                const int rowk = c >> 4;
                const int srck = (c & 15) ^ (rowk & 7);
                gload_lds16(K + (size_t)(kv0 + 64 + rowk) * D + h * HD + srck * 8,
                            &Ks[cur ^ 1][(r * 256 + wid * 64) * 8]);
            }
        }

        const bool active = kv0 <= wrow0 + 31;  // wave-uniform
        if (active) {
            // S^T tile: sf[mi][nt][r] = S[q=wrow0+mi*16+rl][k=kv0+nt*16+g*4+r]
            f32x4 sf[2][4];
#pragma unroll
            for (int mi = 0; mi < 2; ++mi)
#pragma unroll
                for (int nt = 0; nt < 4; ++nt) sf[mi][nt] = f32x4{0.f, 0.f, 0.f, 0.f};
#pragma unroll
            for (int nt = 0; nt < 4; ++nt) {
                const int row = nt * 16 + rl;
#pragma unroll
                for (int ks = 0; ks < 4; ++ks) {
                    bf16x8 kf = *(const bf16x8*)&Ks[cur][row * 128 + (((ks * 4 + g) ^ (row & 7)) << 3)];
                    sf[0][nt] = mfma16(kf, qf[0][ks], sf[0][nt]);
                    sf[1][nt] = mfma16(kf, qf[1][ks], sf[1][nt]);
                }
            }

            const bool needMask = (kv0 + 63 > wrow0);  // wave-uniform
            float cf2[2];
            bool chg = false;
#pragma unroll
            for (int mi = 0; mi < 2; ++mi) {
                const int qrow = wrow0 + mi * 16 + rl;
                float mx = -1e30f;
                if (needMask) {
#pragma unroll
                    for (int nt = 0; nt < 4; ++nt)
#pragma unroll
                        for (int r = 0; r < 4; ++r) {
                            const int kcol = kv0 + nt * 16 + g * 4 + r;
                            float s = sf[mi][nt][r];
                            s = (kcol > qrow) ? -1e30f : s;
                            sf[mi][nt][r] = s;
                            mx = fmaxf(mx, s);
                        }
                } else {
#pragma unroll
                    for (int nt = 0; nt < 4; ++nt)
#pragma unroll
                        for (int r = 0; r < 4; ++r) mx = fmaxf(mx, sf[mi][nt][r]);
                }
                mx = fmaxf(mx, __shfl_xor(mx, 16));
                mx = fmaxf(mx, __shfl_xor(mx, 32));
                const float mn = fmaxf(m2s[mi], mx);
                cf2[mi] = __builtin_amdgcn_exp2f(m2s[mi] - mn);
                chg |= (mn > m2s[mi]);
                m2s[mi] = mn;
                float rs = 0.f;
#pragma unroll
                for (int nt = 0; nt < 4; ++nt)
#pragma unroll
                    for (int r = 0; r < 4; ++r) {
                        const float p = __builtin_amdgcn_exp2f(sf[mi][nt][r] - mn);
                        sf[mi][nt][r] = p;
                        rs += p;
                    }
                rs += __shfl_xor(rs, 16);
                rs += __shfl_xor(rs, 32);
                lsum[mi] = lsum[mi] * cf2[mi] + rs;
            }

            if (__any((int)chg)) {
#pragma unroll
                for (int mi = 0; mi < 2; ++mi)
#pragma unroll
                    for (int nt = 0; nt < 8; ++nt)
#pragma unroll
                        for (int r = 0; r < 4; ++r) accO[mi][nt][r] *= cf2[mi];
            }

            // P -> LDS (bf16, swizzled at 16B-chunk granularity), 8B packed writes
            unsigned short* myP = Ps[wid];
#pragma unroll
            for (int mi = 0; mi < 2; ++mi) {
                const int row = mi * 16 + rl;
                const int rx = row & 7;
#pragma unroll
                for (int nt = 0; nt < 4; ++nt) {
                    ushort4_t v;
#pragma unroll
                    for (int r = 0; r < 4; ++r) v[r] = f2bf(sf[mi][nt][r]);
                    const int chunk = nt * 2 + (g >> 1);
                    *(ushort4_t*)&myP[row * 64 + ((chunk ^ rx) << 3) + ((g & 1) << 2)] = v;
                }
            }
        }
        __syncthreads();  // drains V + K-next staging

        if (active) {
            unsigned short* myP = Ps[wid];
#pragma unroll
            for (int ks = 0; ks < 2; ++ks) {
                bf16x8 pa[2];
#pragma unroll
                for (int mi = 0; mi < 2; ++mi) {
                    const int row = mi * 16 + rl;
                    pa[mi] = *(const bf16x8*)&myP[row * 64 + (((ks * 4 + g) ^ (row & 7)) << 3)];
                }
#pragma unroll
                for (int nt = 0; nt < 8; ++nt) {
                    const int vrow = nt * 16 + rl;
                    bf16x8 vf = *(const bf16x8*)&Vs[vrow * 64 + (((ks * 4 + g) ^ (vrow & 7)) << 3)];
                    accO[0][nt] = mfma16(vf, pa[0], accO[0][nt]);
                    accO[1][nt] = mfma16(vf, pa[1], accO[1][nt]);
                }
            }
        }
        __syncthreads();  // all PV reads done before next iter's V stage
        cur ^= 1;
    }

    // accO[mi][nt][r] = O[q=wrow0+mi*16+rl][hd = nt*16 + g*4 + r]
#pragma unroll
    for (int mi = 0; mi < 2; ++mi) {
        const float inv = 1.0f / lsum[mi];
        const int qrow = wrow0 + mi * 16 + rl;
#pragma unroll
        for (int nt = 0; nt < 8; ++nt) {
            ushort4_t v;
#pragma unroll
            for (int r = 0; r < 4; ++r) v[r] = f2bf(accO[mi][nt][r] * inv);
            *(ushort4_t*)&O[(size_t)qrow * D + h * HD + nt * 16 + g * 4] = v;
        }
    }
}

// ---------------- launch ----------------------------------------------------
extern "C" void kernel_launch(void* const* d_in, const int* in_sizes, int n_in,
                              void* d_out, int out_size, void* d_ws, size_t ws_size,
                              hipStream_t stream) {
    const float* hs   = (const float*)d_in[0];
    const float* cosT = (const float*)d_in[2];
    const float* sinT = (const float*)d_in[3];
    const float* Wq   = (const float*)d_in[4];
    const float* Wk   = (const float*)d_in[5];
    const float* Wv   = (const float*)d_in[6];
    const float* Wo   = (const float*)d_in[7];

    char* ws = (char*)d_ws;
    const size_t MB = 1ull << 20;
    unsigned short* hsb = (unsigned short*)(ws);             // 16 MB  [S][D]
    unsigned short* wqb = (unsigned short*)(ws + 16 * MB);   // 32 MB  [D][D]
    unsigned short* wkb = (unsigned short*)(ws + 48 * MB);
    unsigned short* wvb = (unsigned short*)(ws + 80 * MB);
    unsigned short* wob = (unsigned short*)(ws + 112 * MB);
    unsigned short* Qb  = (unsigned short*)(ws + 144 * MB);  // 16 MB [S][D]
    unsigned short* Kb  = (unsigned short*)(ws + 160 * MB);  // 16 MB [S][D]
    unsigned short* Vt  = (unsigned short*)(ws + 176 * MB);  // 16 MB [D][S] (V^T)
    unsigned short* AOb = (unsigned short*)(ws + 192 * MB);  // 16 MB [S][D]

    cvt_f32_bf16<<<4096, 256, 0, stream>>>(hs, hsb);
    cvt_f32_bf16<<<8192, 256, 0, stream>>>(Wq, wqb);
    cvt_f32_bf16<<<8192, 256, 0, stream>>>(Wk, wkb);
    cvt_f32_bf16<<<8192, 256, 0, stream>>>(Wv, wvb);
    cvt_f32_bf16<<<8192, 256, 0, stream>>>(Wo, wob);

    dim3 gg(D / 128, S / 128);
    gemm_bt<0><<<gg, 256, 0, stream>>>(hsb, wqb, Qb, S, D, D);
    gemm_bt<0><<<gg, 256, 0, stream>>>(hsb, wkb, Kb, S, D, D);
    gemm_bt<1><<<gg, 256, 0, stream>>>(hsb, wvb, Vt, S, D, D);

    rope_kernel<<<2048, 256, 0, stream>>>(Qb, Kb, cosT, sinT);

    flash_attn<<<dim3(NQT * H), 256, 0, stream>>>(Qb, Kb, Vt, AOb);

    gemm_bt<2><<<gg, 256, 0, stream>>>(AOb, wob, (float*)d_out, S, D, D);
}

// Round 4
// 498.088 us; speedup vs baseline: 1.3260x; 1.1125x over previous
//
#include <hip/hip_runtime.h>
#include <hip/hip_bf16.h>
#include <stdint.h>

#define DEV __device__ __forceinline__

typedef __bf16 bf16x8 __attribute__((ext_vector_type(8)));
typedef float f32x4 __attribute__((ext_vector_type(4)));
typedef unsigned short ushort8_t __attribute__((ext_vector_type(8)));
typedef unsigned short ushort4_t __attribute__((ext_vector_type(4)));

constexpr int S = 2048;
constexpr int D = 4096;
constexpr int H = 32;
constexpr int HD = 128;
constexpr float kSc = 0.08838834764831845f * 1.4426950408889634f;  // 1/sqrt(HD) * log2(e)

DEV unsigned short f2bf(float f) {
    uint32_t u = __builtin_bit_cast(uint32_t, f);
    u += 0x7fffu + ((u >> 16) & 1u);
    return (unsigned short)(u >> 16);
}
DEV float bf2f(unsigned short h) {
    uint32_t u = ((uint32_t)h) << 16;
    return __builtin_bit_cast(float, u);
}

DEV void gload_lds16(const void* g, void* l) {
    __builtin_amdgcn_global_load_lds(
        (const __attribute__((address_space(1))) void*)g,
        (__attribute__((address_space(3))) void*)l,
        16, 0, 0);
}

DEV f32x4 mfma16(bf16x8 a, bf16x8 b, f32x4 c) {
    return __builtin_amdgcn_mfma_f32_16x16x32_bf16(a, b, c, 0, 0, 0);
}

// ---------------- fp32 -> bf16 convert, all 5 tensors in one dispatch -------
// grid: 4096 blocks for hs (8.4M elems) + 4*8192 blocks for the weights.
__global__ __launch_bounds__(256) void cvt_all(const float* __restrict__ hs,
                                               const float* __restrict__ w0,
                                               const float* __restrict__ w1,
                                               const float* __restrict__ w2,
                                               const float* __restrict__ w3,
                                               unsigned short* __restrict__ hsb,
                                               unsigned short* __restrict__ o0,
                                               unsigned short* __restrict__ o1,
                                               unsigned short* __restrict__ o2,
                                               unsigned short* __restrict__ o3) {
    const int b = blockIdx.x;
    const float* in;
    unsigned short* out;
    size_t blk;
    if (b < 4096) {
        in = hs; out = hsb; blk = (size_t)b;
    } else {
        const int i = b - 4096;
        const int w = i >> 13;
        const int r = i & 8191;
        in  = (w == 0) ? w0 : (w == 1) ? w1 : (w == 2) ? w2 : w3;
        out = (w == 0) ? o0 : (w == 1) ? o1 : (w == 2) ? o2 : o3;
        blk = (size_t)r;
    }
    const size_t i8 = blk * 256 + threadIdx.x;  // index in units of 8 elems
    f32x4 a = ((const f32x4*)in)[2 * i8];
    f32x4 c = ((const f32x4*)in)[2 * i8 + 1];
    ushort8_t o;
    o[0] = f2bf(a[0]); o[1] = f2bf(a[1]); o[2] = f2bf(a[2]); o[3] = f2bf(a[3]);
    o[4] = f2bf(c[0]); o[5] = f2bf(c[1]); o[6] = f2bf(c[2]); o[7] = f2bf(c[3]);
    ((ushort8_t*)out)[i8] = o;
}

// ---------------- fused QKV GEMM -------------------------------------------
// C[m][n] = sum_k hs[m][k] * W[n][k] for W in {Wq,Wk,Wv} selected per block.
// Grid: 1536 blocks (96 n-tiles x 16 m-tiles), XCD-chunked swizzle.
__global__ __launch_bounds__(256) void gemm_qkv(const unsigned short* __restrict__ A,
                                                const unsigned short* __restrict__ wq,
                                                const unsigned short* __restrict__ wk,
                                                const unsigned short* __restrict__ wv,
                                                unsigned short* __restrict__ Qb,
                                                unsigned short* __restrict__ Kb,
                                                unsigned short* __restrict__ Vt) {
    __shared__ unsigned short As[128 * 64];
    __shared__ unsigned short Bs[128 * 64];
    const int t = threadIdx.x;
    const int lane = t & 63;
    const int wid = t >> 6;
    const int g = lane >> 4;
    const int rl = lane & 15;

    const int bid = blockIdx.x;                 // 1536 = 8 * 192
    const int wg = (bid & 7) * 192 + (bid >> 3);  // XCD-chunked bijective swizzle
    const int xx = wg % 96;
    const int yy = wg / 96;
    const int m0 = yy * 128;
    const int n0g = xx * 128;
    const int wsel = n0g >> 12;                 // 0:Q 1:K 2:V
    const int n0 = n0g & 4095;
    const unsigned short* B = (wsel == 0) ? wq : (wsel == 1) ? wk : wv;

    const int wm = (wid >> 1) * 64;
    const int wn = (wid & 1) * 64;
    constexpr int K = D, M = S, N = D;

    f32x4 acc[4][4] = {};

    for (int kt = 0; kt < K; kt += 64) {
#pragma unroll
        for (int r = 0; r < 4; ++r) {
            const int c = r * 256 + t;
            const int row = c >> 3;
            const int src = (c & 7) ^ (row & 7);
            const int dstChunk = r * 256 + wid * 64;
            gload_lds16(A + (size_t)(m0 + row) * K + kt + src * 8, &As[dstChunk * 8]);
            gload_lds16(B + (size_t)(n0 + row) * K + kt + src * 8, &Bs[dstChunk * 8]);
        }
        __syncthreads();
#pragma unroll
        for (int ks = 0; ks < 2; ++ks) {
            bf16x8 af[4], bfv[4];
#pragma unroll
            for (int i = 0; i < 4; ++i) {
                const int rowa = wm + i * 16 + rl;
                af[i] = *(const bf16x8*)&As[rowa * 64 + (((ks * 4 + g) ^ (rowa & 7)) << 3)];
                const int rowb = wn + i * 16 + rl;
                bfv[i] = *(const bf16x8*)&Bs[rowb * 64 + (((ks * 4 + g) ^ (rowb & 7)) << 3)];
            }
#pragma unroll
            for (int mi = 0; mi < 4; ++mi)
#pragma unroll
                for (int ni = 0; ni < 4; ++ni)
                    acc[mi][ni] = mfma16(af[mi], bfv[ni], acc[mi][ni]);
        }
        __syncthreads();
    }

#pragma unroll
    for (int mi = 0; mi < 4; ++mi) {
#pragma unroll
        for (int ni = 0; ni < 4; ++ni) {
            const int grow = m0 + wm + mi * 16 + g * 4;  // +r
            const int gcol = n0 + wn + ni * 16 + rl;
            if (wsel == 2) {  // V: transposed store  Vt[n][m]
                ushort4_t v;
#pragma unroll
                for (int r = 0; r < 4; ++r) v[r] = f2bf(acc[mi][ni][r]);
                *(ushort4_t*)&Vt[(size_t)gcol * M + grow] = v;
            } else {
                unsigned short* o = (wsel == 0) ? Qb : Kb;
#pragma unroll
                for (int r = 0; r < 4; ++r)
                    o[(size_t)(grow + r) * N + gcol] = f2bf(acc[mi][ni][r]);
            }
        }
    }
}

// ---------------- O-projection GEMM: fp32 C = A * Wo^T ----------------------
__global__ __launch_bounds__(256) void gemm_out(const unsigned short* __restrict__ A,
                                                const unsigned short* __restrict__ B,
                                                float* __restrict__ C) {
    __shared__ unsigned short As[128 * 64];
    __shared__ unsigned short Bs[128 * 64];
    const int t = threadIdx.x;
    const int lane = t & 63;
    const int wid = t >> 6;
    const int g = lane >> 4;
    const int rl = lane & 15;

    const int bid = blockIdx.x;                // 512 = 8 * 64
    const int wg = (bid & 7) * 64 + (bid >> 3);
    const int xx = wg % 32;
    const int yy = wg / 32;
    const int m0 = yy * 128;
    const int n0 = xx * 128;

    const int wm = (wid >> 1) * 64;
    const int wn = (wid & 1) * 64;
    constexpr int K = D, N = D;

    f32x4 acc[4][4] = {};

    for (int kt = 0; kt < K; kt += 64) {
#pragma unroll
        for (int r = 0; r < 4; ++r) {
            const int c = r * 256 + t;
            const int row = c >> 3;
            const int src = (c & 7) ^ (row & 7);
            const int dstChunk = r * 256 + wid * 64;
            gload_lds16(A + (size_t)(m0 + row) * K + kt + src * 8, &As[dstChunk * 8]);
            gload_lds16(B + (size_t)(n0 + row) * K + kt + src * 8, &Bs[dstChunk * 8]);
        }
        __syncthreads();
#pragma unroll
        for (int ks = 0; ks < 2; ++ks) {
            bf16x8 af[4], bfv[4];
#pragma unroll
            for (int i = 0; i < 4; ++i) {
                const int rowa = wm + i * 16 + rl;
                af[i] = *(const bf16x8*)&As[rowa * 64 + (((ks * 4 + g) ^ (rowa & 7)) << 3)];
                const int rowb = wn + i * 16 + rl;
                bfv[i] = *(const bf16x8*)&Bs[rowb * 64 + (((ks * 4 + g) ^ (rowb & 7)) << 3)];
            }
#pragma unroll
            for (int mi = 0; mi < 4; ++mi)
#pragma unroll
                for (int ni = 0; ni < 4; ++ni)
                    acc[mi][ni] = mfma16(af[mi], bfv[ni], acc[mi][ni]);
        }
        __syncthreads();
    }

#pragma unroll
    for (int mi = 0; mi < 4; ++mi) {
#pragma unroll
        for (int ni = 0; ni < 4; ++ni) {
            const int grow = m0 + wm + mi * 16 + g * 4;
            const int gcol = n0 + wn + ni * 16 + rl;
#pragma unroll
            for (int r = 0; r < 4; ++r)
                C[(size_t)(grow + r) * N + gcol] = acc[mi][ni][r];
        }
    }
}

// ---------------- RoPE in place on Q and K ([S][D] bf16) --------------------
__global__ __launch_bounds__(256) void rope_kernel(unsigned short* __restrict__ Qb,
                                                   unsigned short* __restrict__ Kb,
                                                   const float* __restrict__ cosT,
                                                   const float* __restrict__ sinT) {
    const int i = blockIdx.x * 256 + threadIdx.x;  // S*H*8 threads
    const int j8 = i & 7;
    const int h = (i >> 3) & 31;
    const int s = i >> 8;
    const size_t base = (size_t)s * D + h * HD + j8 * 8;
    const float* cp = cosT + s * HD + j8 * 8;
    const float* sp = sinT + s * HD + j8 * 8;
    float c1[8], s1[8], c2[8], s2[8];
#pragma unroll
    for (int k = 0; k < 8; ++k) { c1[k] = cp[k]; s1[k] = sp[k]; c2[k] = cp[k + 64]; s2[k] = sp[k + 64]; }

#pragma unroll
    for (int w = 0; w < 2; ++w) {
        unsigned short* p = (w == 0 ? Qb : Kb) + base;
        const float f = (w == 0) ? kSc : 1.0f;
        ushort8_t x1 = *(ushort8_t*)p;
        ushort8_t x2 = *(ushort8_t*)(p + 64);
        ushort8_t o1, o2;
#pragma unroll
        for (int k = 0; k < 8; ++k) {
            const float a = bf2f(x1[k]);
            const float b = bf2f(x2[k]);
            o1[k] = f2bf((a * c1[k] - b * s1[k]) * f);
            o2[k] = f2bf((b * c2[k] + a * s2[k]) * f);
        }
        *(ushort8_t*)p = o1;
        *(ushort8_t*)(p + 64) = o2;
    }
}

// ---------------- causal flash attention (swapped-operand MFMA) -------------
constexpr int NQT = S / 128;  // 16 q-tiles
__global__ __launch_bounds__(256, 2) void flash_attn(const unsigned short* __restrict__ Q,
                                                     const unsigned short* __restrict__ K,
                                                     const unsigned short* __restrict__ V,
                                                     unsigned short* __restrict__ O) {
    __shared__ unsigned short Ks[2][64 * 128];  // [kv][hd], swizzled, dbuf
    __shared__ unsigned short Vs[128 * 64];     // [hd][kv], swizzled
    __shared__ unsigned short Ps[4][32 * 64];   // per-wave P, swizzled

    const int t = threadIdx.x;
    const int lane = t & 63;
    const int wid = t >> 6;
    const int g = lane >> 4;
    const int rl = lane & 15;
    const int bid = blockIdx.x;
    const int qt = (NQT - 1) - (bid >> 5);  // heavy tiles first
    const int h = bid & 31;                 // head in low bits: head-affine XCD
    const int q0 = qt * 128;
    const int wrow0 = q0 + wid * 32;

    bf16x8 qf[2][4];
#pragma unroll
    for (int mi = 0; mi < 2; ++mi) {
        const unsigned short* qp = Q + (size_t)(wrow0 + mi * 16 + rl) * D + h * HD;
#pragma unroll
        for (int ks = 0; ks < 4; ++ks) qf[mi][ks] = *(const bf16x8*)(qp + ks * 32 + g * 8);
    }

    f32x4 accO[2][8] = {};
    float m2s[2] = {-1e30f, -1e30f};
    float lsum[2] = {0.f, 0.f};

    // prologue: stage K tile 0 into buf 0
#pragma unroll
    for (int r = 0; r < 4; ++r) {
        const int c = r * 256 + t;
        const int rowk = c >> 4;
        const int srck = (c & 15) ^ (rowk & 7);
        gload_lds16(K + (size_t)rowk * D + h * HD + srck * 8,
                    &Ks[0][(r * 256 + wid * 64) * 8]);
    }
    __syncthreads();

    int cur = 0;
    const int ntiles = 2 * qt + 2;
    for (int kv = 0; kv < ntiles; ++kv) {
        const int kv0 = kv * 64;
        // stage V[kv] (single buffer) + prefetch K[kv+1] into other buffer
#pragma unroll
        for (int r = 0; r < 4; ++r) {
            const int c = r * 256 + t;
            const int rowv = c >> 3;
            const int srcv = (c & 7) ^ (rowv & 7);
            gload_lds16(V + (size_t)(h * HD + rowv) * S + kv0 + srcv * 8,
                        &Vs[(r * 256 + wid * 64) * 8]);
        }
        if (kv + 1 < ntiles) {
#pragma unroll
            for (int r = 0; r < 4; ++r) {
                const int c = r * 256 + t;
                const int rowk = c >> 4;
                const int srck = (c & 15) ^ (rowk & 7);
                gload_lds16(K + (size_t)(kv0 + 64 + rowk) * D + h * HD + srck * 8,
                            &Ks[cur ^ 1][(r * 256 + wid * 64) * 8]);
            }
        }

        const bool active = kv0 <= wrow0 + 31;  // wave-uniform
        if (active) {
            // sf[mi][nt][r] = S[q=wrow0+mi*16+rl][k=kv0+nt*16+g*4+r]
            f32x4 sf[2][4];
#pragma unroll
            for (int mi = 0; mi < 2; ++mi)
#pragma unroll
                for (int nt = 0; nt < 4; ++nt) sf[mi][nt] = f32x4{0.f, 0.f, 0.f, 0.f};
            __builtin_amdgcn_s_setprio(1);
#pragma unroll
            for (int nt = 0; nt < 4; ++nt) {
                const int row = nt * 16 + rl;
#pragma unroll
                for (int ks = 0; ks < 4; ++ks) {
                    bf16x8 kf = *(const bf16x8*)&Ks[cur][row * 128 + (((ks * 4 + g) ^ (row & 7)) << 3)];
                    sf[0][nt] = mfma16(kf, qf[0][ks], sf[0][nt]);
                    sf[1][nt] = mfma16(kf, qf[1][ks], sf[1][nt]);
                }
            }
            __builtin_amdgcn_s_setprio(0);

            const bool needMask = (kv0 + 63 > wrow0);  // wave-uniform
            float cf2[2];
            bool chg = false;
#pragma unroll
            for (int mi = 0; mi < 2; ++mi) {
                const int qrow = wrow0 + mi * 16 + rl;
                float mx = -1e30f;
                if (needMask) {
#pragma unroll
                    for (int nt = 0; nt < 4; ++nt)
#pragma unroll
                        for (int r = 0; r < 4; ++r) {
                            const int kcol = kv0 + nt * 16 + g * 4 + r;
                            float s = sf[mi][nt][r];
                            s = (kcol > qrow) ? -1e30f : s;
                            sf[mi][nt][r] = s;
                            mx = fmaxf(mx, s);
                        }
                } else {
#pragma unroll
                    for (int nt = 0; nt < 4; ++nt)
#pragma unroll
                        for (int r = 0; r < 4; ++r) mx = fmaxf(mx, sf[mi][nt][r]);
                }
                mx = fmaxf(mx, __shfl_xor(mx, 16));
                mx = fmaxf(mx, __shfl_xor(mx, 32));
                const float mn = fmaxf(m2s[mi], mx);
                cf2[mi] = __builtin_amdgcn_exp2f(m2s[mi] - mn);
                chg |= (mn > m2s[mi]);
                m2s[mi] = mn;
                float rs = 0.f;
#pragma unroll
                for (int nt = 0; nt < 4; ++nt)
#pragma unroll
                    for (int r = 0; r < 4; ++r) {
                        const float p = __builtin_amdgcn_exp2f(sf[mi][nt][r] - mn);
                        sf[mi][nt][r] = p;
                        rs += p;
                    }
                rs += __shfl_xor(rs, 16);
                rs += __shfl_xor(rs, 32);
                lsum[mi] = lsum[mi] * cf2[mi] + rs;
            }

            if (__any((int)chg)) {
#pragma unroll
                for (int mi = 0; mi < 2; ++mi)
#pragma unroll
                    for (int nt = 0; nt < 8; ++nt)
#pragma unroll
                        for (int r = 0; r < 4; ++r) accO[mi][nt][r] *= cf2[mi];
            }

            // P -> LDS (bf16, swizzled at 16B-chunk granularity), 8B packed writes
            unsigned short* myP = Ps[wid];
#pragma unroll
            for (int mi = 0; mi < 2; ++mi) {
                const int row = mi * 16 + rl;
                const int rx = row & 7;
#pragma unroll
                for (int nt = 0; nt < 4; ++nt) {
                    ushort4_t v;
#pragma unroll
                    for (int r = 0; r < 4; ++r) v[r] = f2bf(sf[mi][nt][r]);
                    const int chunk = nt * 2 + (g >> 1);
                    *(ushort4_t*)&myP[row * 64 + ((chunk ^ rx) << 3) + ((g & 1) << 2)] = v;
                }
            }
        }
        __syncthreads();  // drains V + K-next staging

        if (active) {
            unsigned short* myP = Ps[wid];
            __builtin_amdgcn_s_setprio(1);
#pragma unroll
            for (int ks = 0; ks < 2; ++ks) {
                bf16x8 pa[2];
#pragma unroll
                for (int mi = 0; mi < 2; ++mi) {
                    const int row = mi * 16 + rl;
                    pa[mi] = *(const bf16x8*)&myP[row * 64 + (((ks * 4 + g) ^ (row & 7)) << 3)];
                }
#pragma unroll
                for (int nt = 0; nt < 8; ++nt) {
                    const int vrow = nt * 16 + rl;
                    bf16x8 vf = *(const bf16x8*)&Vs[vrow * 64 + (((ks * 4 + g) ^ (vrow & 7)) << 3)];
                    accO[0][nt] = mfma16(vf, pa[0], accO[0][nt]);
                    accO[1][nt] = mfma16(vf, pa[1], accO[1][nt]);
                }
            }
            __builtin_amdgcn_s_setprio(0);
        }
        __syncthreads();  // all PV reads done before next iter's V stage
        cur ^= 1;
    }

    // accO[mi][nt][r] = O[q=wrow0+mi*16+rl][hd = nt*16 + g*4 + r]
#pragma unroll
    for (int mi = 0; mi < 2; ++mi) {
        const float inv = 1.0f / lsum[mi];
        const int qrow = wrow0 + mi * 16 + rl;
#pragma unroll
        for (int nt = 0; nt < 8; ++nt) {
            ushort4_t v;
#pragma unroll
            for (int r = 0; r < 4; ++r) v[r] = f2bf(accO[mi][nt][r] * inv);
            *(ushort4_t*)&O[(size_t)qrow * D + h * HD + nt * 16 + g * 4] = v;
        }
    }
}

// ---------------- launch ----------------------------------------------------
extern "C" void kernel_launch(void* const* d_in, const int* in_sizes, int n_in,
                              void* d_out, int out_size, void* d_ws, size_t ws_size,
                              hipStream_t stream) {
    const float* hs   = (const float*)d_in[0];
    const float* cosT = (const float*)d_in[2];
    const float* sinT = (const float*)d_in[3];
    const float* Wq   = (const float*)d_in[4];
    const float* Wk   = (const float*)d_in[5];
    const float* Wv   = (const float*)d_in[6];
    const float* Wo   = (const float*)d_in[7];

    char* ws = (char*)d_ws;
    const size_t MB = 1ull << 20;
    unsigned short* hsb = (unsigned short*)(ws);             // 16 MB  [S][D]
    unsigned short* wqb = (unsigned short*)(ws + 16 * MB);   // 32 MB  [D][D]
    unsigned short* wkb = (unsigned short*)(ws + 48 * MB);
    unsigned short* wvb = (unsigned short*)(ws + 80 * MB);
    unsigned short* wob = (unsigned short*)(ws + 112 * MB);
    unsigned short* Qb  = (unsigned short*)(ws + 144 * MB);  // 16 MB [S][D]
    unsigned short* Kb  = (unsigned short*)(ws + 160 * MB);  // 16 MB [S][D]
    unsigned short* Vt  = (unsigned short*)(ws + 176 * MB);  // 16 MB [D][S] (V^T)
    unsigned short* AOb = (unsigned short*)(ws + 192 * MB);  // 16 MB [S][D]

    cvt_all<<<4096 + 4 * 8192, 256, 0, stream>>>(hs, Wq, Wk, Wv, Wo,
                                                 hsb, wqb, wkb, wvb, wob);

    gemm_qkv<<<1536, 256, 0, stream>>>(hsb, wqb, wkb, wvb, Qb, Kb, Vt);

    rope_kernel<<<2048, 256, 0, stream>>>(Qb, Kb, cosT, sinT);

    flash_attn<<<dim3(NQT * H), 256, 0, stream>>>(Qb, Kb, Vt, AOb);

    gemm_out<<<512, 256, 0, stream>>>(AOb, wob, (float*)d_out);
}